// Round 15
// baseline (6991.366 us; speedup 1.0000x reference)
//
#include <hip/hip_runtime.h>
#include <hip/hip_bf16.h>

// Problem: B=64, S=512, D=1024, gates N=4096, K=2048 (x ++ h)

typedef __attribute__((ext_vector_type(8))) short bf16x8;
typedef __attribute__((ext_vector_type(16))) float f32x16;
typedef __attribute__((ext_vector_type(4)))  int   i32x4;

#define AT_RLX __ATOMIC_RELAXED
#define SC_AGT __HIP_MEMORY_SCOPE_AGENT

// ---------- prep kernels ----------

// Wt[n*2048 + k] = bf16(W[k*4096 + n])   (B^T layout: 8 consecutive k per lane)
__global__ __launch_bounds__(256) void conv_w(const float* __restrict__ W,
                                              __hip_bfloat16* __restrict__ Wt) {
    size_t id = (size_t)blockIdx.x * 256 + threadIdx.x;   // < 2048*4096
    int k = (int)(id >> 12);
    int n = (int)(id & 4095);
    Wt[(size_t)n * 2048 + k] = __float2bfloat16(W[id]);
}

// Xt[(s*64+b)*1024 + d] = bf16(X[(b*512+s)*1024 + d])
__global__ __launch_bounds__(256) void conv_x(const float* __restrict__ X,
                                              __hip_bfloat16* __restrict__ Xt) {
    size_t id = (size_t)blockIdx.x * 256 + threadIdx.x;   // < 64*512*1024
    int d   = (int)(id & 1023);
    int row = (int)(id >> 10);
    int s = row >> 6;
    int b = row & 63;
    Xt[id] = __float2bfloat16(X[(((size_t)b * 512 + s) << 10) + d]);
}

// zero comb2 epoch-granules; prefill ALL 8 h mirrors with h(-1); zero hflag.
__global__ __launch_bounds__(256) void init_misc(const float* __restrict__ hx,
                                                 __hip_bfloat16* __restrict__ h,
                                                 unsigned long long* __restrict__ comb2,
                                                 unsigned int* __restrict__ hflag) {
    int id = blockIdx.x * 256 + threadIdx.x;              // grid 2048 -> 524288
    if (id < 262144) comb2[id] = 0ULL;
    h[id] = __float2bfloat16(hx[id & 1023]);              // 8 x [64][1024] mirrors
    if (id < 1024)  hflag[id] = 0u;
}

// ---------- coherence-point primitives ----------
// 16B IF-coherent load (sc0 sc1). Caller must vm_wait0() before consuming.
__device__ __forceinline__ i32x4 ld_cp16(const void* p) {
    i32x4 r;
    asm volatile("global_load_dwordx4 %0, %1, off sc0 sc1"
                 : "=&v"(r) : "v"(p) : "memory");
    return r;
}
__device__ __forceinline__ void vm_wait0() {
    asm volatile("s_waitcnt vmcnt(0)" ::: "memory");
    __builtin_amdgcn_sched_barrier(0);
}
// 8B write EXECUTED AT the IF coherence point: returning agent-scope exchange.
// vmcnt clears only when the old value returns from IF (round-5 lesson).
__device__ __forceinline__ void xchg8u(unsigned long long* p, unsigned long long v) {
    unsigned long long old = __hip_atomic_exchange(p, v, AT_RLX, SC_AGT);
    asm volatile("" :: "v"(old));
}

// ---------- fused persistent recurrence ----------
// 256 WGs x 256 thr (1 WG/CU). WG b: nt=b>>1 (col tile), mt=b&1 (row block).
//
// NEW vs r14: 8-WAY MIRRORED h. The h-broadcast is ~1M sc-transactions/step on a
// 128KB footprint -> ~1K same-line requests serialize on single IF banks (the
// hypothesized 4-6us/step congestion). Consumers publish h to 8 mirror copies
// (8 pipelined xchgs, ONE drain); producer WG b reads mirror b>>5 -> per-line
// readers drop 128->16 WGs, spreading load over 8x more banks.
//
// comb hop = epoch granules (r14): u64 {lo32 = f32 value, hi32 = s+1}; plain
// fire-and-forget 8B stores; consumer polls its own granules (readiness==data).
//
// WAR safety: consumer's reduce barrier collectively confirms all 128 producers
// published comb(s) => they finished reading h(s-1) mirrors => mirror overwrite
// at s is safe. Producer writes comb(s+1) only after hflag(s), set after ALL
// mirror xchgs returned from IF (vmcnt0 at the barrier).
// LDS double-buffered (s&1): no post-publish barrier.
__global__ __launch_bounds__(256, 1) void lstm_fused(
    const __hip_bfloat16* __restrict__ Xt,
    const __hip_bfloat16* __restrict__ Wt,
    __hip_bfloat16* __restrict__ h,          // [8][64][1024] mirrors
    const float* __restrict__ bias,
    const float* __restrict__ lnw,
    const float* __restrict__ lnb,
    const float* __restrict__ cx,
    unsigned long long* __restrict__ comb2,  // [64][4096] epoch-granules
    float* __restrict__ out,
    unsigned int* __restrict__ hflag)        // 64 x 16-u32 padded
{
    const int tid  = threadIdx.x;
    const int lane = tid & 63;
    const int wv   = tid >> 6;          // wave in WG: 0..3
    const int b    = blockIdx.x;        // 0..255

    const int nt = b >> 1;              // col tile 0..127
    const int mt = b & 1;               // row block 0..1
    const int kc = wv;                  // K chunk 0..3  (512 each)
    const int cl = lane & 31;
    const int kh = (lane >> 5) * 8;
    const int n0 = nt * 32;
    const int mg = b >> 5;              // h mirror group 0..7

    __shared__ float lds_f[8192];       // double-buffered 4 x 32 x 32 partials
    __shared__ float red[8];

    // ---- load this wave's B chunk into registers, once ----
    const short* bp = (const short*)Wt + (size_t)(n0 + cl) * 2048 + kc * 512 + kh;
    bf16x8 breg[32];
#pragma unroll
    for (int i = 0; i < 32; ++i) breg[i] = *(const bf16x8*)(bp + i * 16);

    // ---- A pointers ----
    const short* xbase = (const short*)Xt + (size_t)(mt * 32 + cl) * 1024 + kc * 512 + kh; // + s*65536
    const short* hrow  = (const short*)h + (size_t)mg * 65536
                       + (size_t)(mt * 32 + cl) * 1024 + (kc - 2) * 512 + kh;   // kc>=2
    const unsigned int* myhf = &hflag[(mt * 32 + cl) * 16];   // h-row flag this lane reads

    // ---- pointwise persistent state + parameter preloads (rows owned by WGs 0..63) ----
    // thread t owns 4 consecutive outputs o = 4t..4t+3.
    float cr[4];
    float bias_r[4][4], lnw_r[4][4], lnb_r[4][4];
    if (b < 64) {
#pragma unroll
        for (int e = 0; e < 4; ++e) cr[e] = cx[4 * tid + e];
#pragma unroll
        for (int g = 0; g < 4; ++g)
#pragma unroll
            for (int e = 0; e < 4; ++e) {
                bias_r[g][e] = bias[1024 * g + 4 * tid + e];
                lnw_r[g][e]  = lnw[1024 * g + 4 * tid + e];
                lnb_r[g][e]  = lnb[1024 * g + 4 * tid + e];
            }
    }

    for (int s = 0; s < 512; ++s) {
        // ================= phase 1: GEMM, split-K reduced in LDS =================
        f32x16 accA, accB;
#pragma unroll
        for (int i = 0; i < 16; ++i) { accA[i] = 0.f; accB[i] = 0.f; }
        if (kc < 2) {
            const short* ap = xbase + (size_t)s * 65536;
#pragma unroll
            for (int i = 0; i < 16; ++i) {
                bf16x8 a0 = *(const bf16x8*)(ap + i * 16);
                bf16x8 a1 = *(const bf16x8*)(ap + (i + 16) * 16);
                accA = __builtin_amdgcn_mfma_f32_32x32x16_bf16(a0, breg[i],      accA, 0, 0, 0);
                accB = __builtin_amdgcn_mfma_f32_32x32x16_bf16(a1, breg[i + 16], accB, 0, 0, 0);
            }
        } else {
            // wait for h(s-1): per-lane poll of the one row flag this lane reads
            while (__hip_atomic_load(myhf, AT_RLX, SC_AGT) < (unsigned int)s)
                __builtin_amdgcn_s_sleep(1);
            asm volatile("" ::: "memory");
            // batched 16B IF-coherent loads from THIS GROUP'S mirror, single drain
            bf16x8 ha[32];
#pragma unroll
            for (int i = 0; i < 32; ++i)
                ha[i] = __builtin_bit_cast(bf16x8, ld_cp16(hrow + i * 16));
            vm_wait0();
#pragma unroll
            for (int i = 0; i < 16; ++i) {
                accA = __builtin_amdgcn_mfma_f32_32x32x16_bf16(ha[i],      breg[i],      accA, 0, 0, 0);
                accB = __builtin_amdgcn_mfma_f32_32x32x16_bf16(ha[i + 16], breg[i + 16], accB, 0, 0, 0);
            }
        }
        float* lbuf = lds_f + (s & 1) * 4096;
#pragma unroll
        for (int r = 0; r < 16; ++r) {
            int rl = (r & 3) + 8 * (r >> 2) + 4 * (lane >> 5);
            lbuf[kc * 1024 + rl * 32 + cl] = accA[r] + accB[r];
        }
        __syncthreads();
        {
            // publish comb tile as epoch-granules: plain 8B stores, fire-and-forget
            unsigned long long ep64 = ((unsigned long long)(unsigned)(s + 1)) << 32;
#pragma unroll
            for (int half = 0; half < 2; ++half) {
                int e = 2 * tid + half * 512;
                float2 p0 = *(const float2*)&lbuf[e];
                float2 p1 = *(const float2*)&lbuf[1024 + e];
                float2 p2 = *(const float2*)&lbuf[2048 + e];
                float2 p3 = *(const float2*)&lbuf[3072 + e];
                float v0 = p0.x + p1.x + p2.x + p3.x;
                float v1 = p0.y + p1.y + p2.y + p3.y;
                size_t g = (size_t)(mt * 32 + (e >> 5)) * 4096 + n0 + (e & 31);
                __hip_atomic_store(&comb2[g],
                    ep64 | __builtin_bit_cast(unsigned int, v0), AT_RLX, SC_AGT);
                __hip_atomic_store(&comb2[g + 1],
                    ep64 | __builtin_bit_cast(unsigned int, v1), AT_RLX, SC_AGT);
            }
        }
        // no drain, no flag, no post barrier (LDS double-buffered)

        // ================= phase 2: pointwise (rows on WGs 0..63) =================
        if (b < 64) {
            const unsigned long long* c2 = comb2 + (size_t)b * 4096;
            unsigned long long q[16];
            unsigned int miss = 0xFFFFu;
            const unsigned int tgt = (unsigned int)(s + 1);
            for (;;) {
#pragma unroll
                for (int g = 0; g < 4; ++g)
#pragma unroll
                    for (int e = 0; e < 4; ++e) {
                        int k = 4 * g + e;
                        if (miss & (1u << k))
                            q[k] = __hip_atomic_load(&c2[1024 * g + 4 * tid + e],
                                                     AT_RLX, SC_AGT);
                    }
                unsigned int nm = 0;
#pragma unroll
                for (int k = 0; k < 16; ++k)
                    if ((miss & (1u << k)) && (unsigned int)(q[k] >> 32) < tgt)
                        nm |= 1u << k;
                miss = nm;
                if (!miss) break;
                __builtin_amdgcn_s_sleep(1);
            }
            float v[4][4];
            float s1 = 0.f, s2 = 0.f;
#pragma unroll
            for (int g = 0; g < 4; ++g)
#pragma unroll
                for (int e = 0; e < 4; ++e) {
                    float x = __builtin_bit_cast(float, (unsigned int)q[4 * g + e])
                            + bias_r[g][e];
                    v[g][e] = x;
                    s1 += x;
                    s2 += x * x;
                }
            for (int off = 32; off; off >>= 1) {
                s1 += __shfl_down(s1, off);
                s2 += __shfl_down(s2, off);
            }
            if (lane == 0) { red[2 * wv] = s1; red[2 * wv + 1] = s2; }
            __syncthreads();   // collective: ALL producers of this row-block confirmed
            float sum = red[0] + red[2] + red[4] + red[6];
            float ssq = red[1] + red[3] + red[5] + red[7];
            float mean = sum * (1.f / 4096.f);
            float var  = ssq * (1.f / 4096.f) - mean * mean;
            float rstd = rsqrtf(var + 1e-5f);
            float hn[4];
#pragma unroll
            for (int e = 0; e < 4; ++e) {
                float yi = (v[0][e] - mean) * rstd * lnw_r[0][e] + lnb_r[0][e];
                float yf = (v[1][e] - mean) * rstd * lnw_r[1][e] + lnb_r[1][e];
                float yo = (v[2][e] - mean) * rstd * lnw_r[2][e] + lnb_r[2][e];
                float yh = (v[3][e] - mean) * rstd * lnw_r[3][e] + lnb_r[3][e];
                float ig = 1.f / (1.f + __expf(-yi));
                float fg = 1.f / (1.f + __expf(-yf));
                float og = 1.f / (1.f + __expf(-yo));
                float hd = tanhf(yh);
                float cn = fg * cr[e] + ig * hd;
                cr[e] = cn;
                hn[e] = og * tanhf(cn);
            }
            // h handoff: publish to ALL 8 MIRRORS (pipelined xchgs, one drain),
            // then flag, then out store (off the critical path).
            unsigned long long hp = 0;
#pragma unroll
            for (int e = 0; e < 4; ++e)
                hp |= (unsigned long long)
                      __builtin_bit_cast(unsigned short, __float2bfloat16(hn[e])) << (16 * e);
            unsigned short* hb = (unsigned short*)h + b * 1024 + 4 * tid;
#pragma unroll
            for (int m = 0; m < 8; ++m)
                xchg8u((unsigned long long*)(hb + m * 65536), hp);
            __syncthreads();   // vmcnt(0): all mirrors at coherence point
            if (tid == 0)
                __hip_atomic_store(&hflag[b * 16], (unsigned int)(s + 1), AT_RLX, SC_AGT);
            float o4[4];
#pragma unroll
            for (int e = 0; e < 4; ++e) o4[e] = hn[e];
            *(float4*)(out + (size_t)b * 524288 + (size_t)s * 1024 + 4 * tid) =
                *(float4*)o4;
        }
    }
}

// ---------- launcher ----------
extern "C" void kernel_launch(void* const* d_in, const int* in_sizes, int n_in,
                              void* d_out, int out_size, void* d_ws, size_t ws_size,
                              hipStream_t stream) {
    const float* X   = (const float*)d_in[0];   // [64,512,1024]
    const float* W   = (const float*)d_in[1];   // [2048,4096]
    const float* bv  = (const float*)d_in[2];   // [4096]
    const float* lnw = (const float*)d_in[3];   // [4096]
    const float* lnb = (const float*)d_in[4];   // [4096]
    const float* hx  = (const float*)d_in[5];   // [1,1024]
    const float* cx  = (const float*)d_in[6];   // [1,1024]
    float* out = (float*)d_out;                 // [64,512,1024]

    char* base = (char*)d_ws;
    __hip_bfloat16*     Wt    = (__hip_bfloat16*)    (base);             // 16 MB
    __hip_bfloat16*     Xt    = (__hip_bfloat16*)    (base + 16777216);  // 64 MB
    unsigned long long* comb2 = (unsigned long long*)(base + 83886080);  // 2 MB
    __hip_bfloat16*     hbuf  = (__hip_bfloat16*)    (base + 85983232);  // 1 MB (8 mirrors)
    unsigned int*       hflag = (unsigned int*)      (base + 87031808);  // 4 KB
    // total ~87.04 MB

    conv_w<<<32768, 256, 0, stream>>>(W, Wt);
    conv_x<<<131072, 256, 0, stream>>>(X, Xt);
    init_misc<<<2048, 256, 0, stream>>>(hx, hbuf, comb2, hflag);

    lstm_fused<<<256, 256, 0, stream>>>(Xt, Wt, hbuf, bv, lnw, lnb, cx, comb2, out,
                                        hflag);
}

// Round 16
// 5048.878 us; speedup vs baseline: 1.3847x; 1.3847x over previous
//
#include <hip/hip_runtime.h>
#include <hip/hip_bf16.h>

// Problem: B=64, S=512, D=1024, gates N=4096, K=2048 (x ++ h)

typedef __attribute__((ext_vector_type(8))) short bf16x8;
typedef __attribute__((ext_vector_type(16))) float f32x16;
typedef __attribute__((ext_vector_type(4)))  int   i32x4;

#define AT_RLX __ATOMIC_RELAXED
#define SC_AGT __HIP_MEMORY_SCOPE_AGENT

// ---------- prep kernels ----------

// Wt[n*2048 + k] = bf16(W[k*4096 + n])   (B^T layout: 8 consecutive k per lane)
__global__ __launch_bounds__(256) void conv_w(const float* __restrict__ W,
                                              __hip_bfloat16* __restrict__ Wt) {
    size_t id = (size_t)blockIdx.x * 256 + threadIdx.x;   // < 2048*4096
    int k = (int)(id >> 12);
    int n = (int)(id & 4095);
    Wt[(size_t)n * 2048 + k] = __float2bfloat16(W[id]);
}

// Xt[(s*64+b)*1024 + d] = bf16(X[(b*512+s)*1024 + d])
__global__ __launch_bounds__(256) void conv_x(const float* __restrict__ X,
                                              __hip_bfloat16* __restrict__ Xt) {
    size_t id = (size_t)blockIdx.x * 256 + threadIdx.x;   // < 64*512*1024
    int d   = (int)(id & 1023);
    int row = (int)(id >> 10);
    int s = row >> 6;
    int b = row & 63;
    Xt[id] = __float2bfloat16(X[(((size_t)b * 512 + s) << 10) + d]);
}

// zero comb2 epoch-granules (epoch 0 = "no step published"); prefill h(-1); zero hflag
__global__ __launch_bounds__(256) void init_misc(const float* __restrict__ hx,
                                                 __hip_bfloat16* __restrict__ h,
                                                 unsigned long long* __restrict__ comb2,
                                                 unsigned int* __restrict__ hflag) {
    int id = blockIdx.x * 256 + threadIdx.x;              // grid 1024 -> 262144
    comb2[id] = 0ULL;
    if (id < 65536) h[id] = __float2bfloat16(hx[id & 1023]);
    if (id < 1024)  hflag[id] = 0u;
}

// ---------- coherence-point primitives ----------
// 16B IF-coherent load (sc0 sc1). Caller must vm_wait0() before consuming.
__device__ __forceinline__ i32x4 ld_cp16(const void* p) {
    i32x4 r;
    asm volatile("global_load_dwordx4 %0, %1, off sc0 sc1"
                 : "=&v"(r) : "v"(p) : "memory");
    return r;
}
__device__ __forceinline__ void vm_wait0() {
    asm volatile("s_waitcnt vmcnt(0)" ::: "memory");
    __builtin_amdgcn_sched_barrier(0);
}
// 8B write EXECUTED AT the IF coherence point: returning agent-scope exchange.
// vmcnt clears only when the old value returns from IF (round-5 lesson). Used ONLY
// for the h publish (it precedes a separate flag, which needs proven arrival).
__device__ __forceinline__ void xchg8u(unsigned long long* p, unsigned long long v) {
    unsigned long long old = __hip_atomic_exchange(p, v, AT_RLX, SC_AGT);
    asm volatile("" :: "v"(old));
}

// ---------- fused persistent recurrence ----------
// 256 WGs x 256 thr (1 WG/CU). WG b: nt=b>>1 (col tile), mt=b&1 (row block).
//
// NEW vs r14: COALESCED h-broadcast. Old per-lane h loads (lane=row) scattered a
// wave's 64 addresses across 32 rows at 2KB stride -> ~1M small IF requests/step
// (request-rate congestion, the hypothesized ~3-4us). Now each h-wave issues 32
// fully-coalesced 1KB loads (instr j = entire half-row j), one drain, stages into
// a per-wave 32KB LDS region (XOR swizzle, G4), then ds_read_b128 fragments.
// ~8x fewer IF transactions; LDS round-trip ~0.25us overlapped.
//
// comb hop = epoch granules (r14): u64 {lo32 = f32 value, hi32 = s+1}; plain
// fire-and-forget 8B stores; consumer polls its own granules (readiness==data).
//
// WAR safety unchanged from r14. LDS partials double-buffered (s&1).
__global__ __launch_bounds__(256, 1) void lstm_fused(
    const __hip_bfloat16* __restrict__ Xt,
    const __hip_bfloat16* __restrict__ Wt,
    __hip_bfloat16* __restrict__ h,
    const float* __restrict__ bias,
    const float* __restrict__ lnw,
    const float* __restrict__ lnb,
    const float* __restrict__ cx,
    unsigned long long* __restrict__ comb2,   // [64][4096] epoch-granules
    float* __restrict__ out,
    unsigned int* __restrict__ hflag)         // 64 x 16-u32 padded
{
    const int tid  = threadIdx.x;
    const int lane = tid & 63;
    const int wv   = tid >> 6;          // wave in WG: 0..3
    const int b    = blockIdx.x;        // 0..255

    const int nt = b >> 1;              // col tile 0..127
    const int mt = b & 1;               // row block 0..1
    const int kc = wv;                  // K chunk 0..3  (512 each)
    const int cl = lane & 31;
    const int hi = lane >> 5;
    const int kh = hi * 8;
    const int n0 = nt * 32;

    __shared__ float lds_f[8192];       // double-buffered 4 x 32 x 32 partials
    __shared__ short hstage[2][16384];  // per-h-wave 32 rows x 512 bf16, XOR-swizzled
    __shared__ float red[8];

    // ---- load this wave's B chunk into registers, once ----
    const short* bp = (const short*)Wt + (size_t)(n0 + cl) * 2048 + kc * 512 + kh;
    bf16x8 breg[32];
#pragma unroll
    for (int i = 0; i < 32; ++i) breg[i] = *(const bf16x8*)(bp + i * 16);

    // ---- A pointers ----
    const short* xbase = (const short*)Xt + (size_t)(mt * 32 + cl) * 1024 + kc * 512 + kh; // + s*65536
    // coalesced h source: lane-contiguous within a half-row
    const short* hsrc = (const short*)h + (size_t)(mt * 32) * 1024 + (kc - 2) * 512 + lane * 8; // kc>=2
    const unsigned int* myhf = &hflag[(mt * 32 + cl) * 16];   // h-row flag this lane reads

    // ---- pointwise persistent state + parameter preloads (rows owned by WGs 0..63) ----
    // thread t owns 4 consecutive outputs o = 4t..4t+3.
    float cr[4];
    float bias_r[4][4], lnw_r[4][4], lnb_r[4][4];
    if (b < 64) {
#pragma unroll
        for (int e = 0; e < 4; ++e) cr[e] = cx[4 * tid + e];
#pragma unroll
        for (int g = 0; g < 4; ++g)
#pragma unroll
            for (int e = 0; e < 4; ++e) {
                bias_r[g][e] = bias[1024 * g + 4 * tid + e];
                lnw_r[g][e]  = lnw[1024 * g + 4 * tid + e];
                lnb_r[g][e]  = lnb[1024 * g + 4 * tid + e];
            }
    }

    for (int s = 0; s < 512; ++s) {
        // ================= phase 1: GEMM, split-K reduced in LDS =================
        f32x16 accA, accB;
#pragma unroll
        for (int i = 0; i < 16; ++i) { accA[i] = 0.f; accB[i] = 0.f; }
        if (kc < 2) {
            const short* ap = xbase + (size_t)s * 65536;
#pragma unroll
            for (int i = 0; i < 16; ++i) {
                bf16x8 a0 = *(const bf16x8*)(ap + i * 16);
                bf16x8 a1 = *(const bf16x8*)(ap + (i + 16) * 16);
                accA = __builtin_amdgcn_mfma_f32_32x32x16_bf16(a0, breg[i],      accA, 0, 0, 0);
                accB = __builtin_amdgcn_mfma_f32_32x32x16_bf16(a1, breg[i + 16], accB, 0, 0, 0);
            }
        } else {
            // wait for h(s-1): per-lane spin on the row flag (wave exits when ALL ready)
            while (__hip_atomic_load(myhf, AT_RLX, SC_AGT) < (unsigned int)s)
                __builtin_amdgcn_s_sleep(1);
            asm volatile("" ::: "memory");
            // COALESCED cooperative load: instr j = half-row j (1KB, lane-contiguous)
            i32x4 hb[32];
#pragma unroll
            for (int j = 0; j < 32; ++j)
                hb[j] = ld_cp16(hsrc + (size_t)j * 1024);
            vm_wait0();
            // stage into this wave's LDS region, XOR-swizzled 16B blocks (G4)
            short* st = &hstage[kc - 2][0];
#pragma unroll
            for (int j = 0; j < 32; ++j)
                *(i32x4*)((char*)(st + j * 512) + ((lane * 16) ^ ((j & 7) << 4))) = hb[j];
            // fragments: lane reads row cl (swizzle-matched); compiler orders lgkmcnt
            const char* rb = (const char*)(st + cl * 512);
            const int swz = (cl & 7) << 4;
#pragma unroll
            for (int i = 0; i < 16; ++i) {
                bf16x8 a0 = *(const bf16x8*)(rb + ((i * 32 + hi * 16) ^ swz));
                bf16x8 a1 = *(const bf16x8*)(rb + ((512 + i * 32 + hi * 16) ^ swz));
                accA = __builtin_amdgcn_mfma_f32_32x32x16_bf16(a0, breg[i],      accA, 0, 0, 0);
                accB = __builtin_amdgcn_mfma_f32_32x32x16_bf16(a1, breg[i + 16], accB, 0, 0, 0);
            }
        }
        float* lbuf = lds_f + (s & 1) * 4096;
#pragma unroll
        for (int r = 0; r < 16; ++r) {
            int rl = (r & 3) + 8 * (r >> 2) + 4 * (lane >> 5);
            lbuf[kc * 1024 + rl * 32 + cl] = accA[r] + accB[r];
        }
        __syncthreads();
        {
            // publish comb tile as epoch-granules: plain 8B stores, fire-and-forget
            unsigned long long ep64 = ((unsigned long long)(unsigned)(s + 1)) << 32;
#pragma unroll
            for (int half = 0; half < 2; ++half) {
                int e = 2 * tid + half * 512;
                float2 p0 = *(const float2*)&lbuf[e];
                float2 p1 = *(const float2*)&lbuf[1024 + e];
                float2 p2 = *(const float2*)&lbuf[2048 + e];
                float2 p3 = *(const float2*)&lbuf[3072 + e];
                float v0 = p0.x + p1.x + p2.x + p3.x;
                float v1 = p0.y + p1.y + p2.y + p3.y;
                size_t g = (size_t)(mt * 32 + (e >> 5)) * 4096 + n0 + (e & 31);
                __hip_atomic_store(&comb2[g],
                    ep64 | __builtin_bit_cast(unsigned int, v0), AT_RLX, SC_AGT);
                __hip_atomic_store(&comb2[g + 1],
                    ep64 | __builtin_bit_cast(unsigned int, v1), AT_RLX, SC_AGT);
            }
        }
        // no drain, no flag, no post barrier (LDS double-buffered)

        // ================= phase 2: pointwise (rows on WGs 0..63) =================
        if (b < 64) {
            const unsigned long long* c2 = comb2 + (size_t)b * 4096;
            unsigned long long q[16];
            unsigned int miss = 0xFFFFu;
            const unsigned int tgt = (unsigned int)(s + 1);
            for (;;) {
#pragma unroll
                for (int g = 0; g < 4; ++g)
#pragma unroll
                    for (int e = 0; e < 4; ++e) {
                        int k = 4 * g + e;
                        if (miss & (1u << k))
                            q[k] = __hip_atomic_load(&c2[1024 * g + 4 * tid + e],
                                                     AT_RLX, SC_AGT);
                    }
                unsigned int nm = 0;
#pragma unroll
                for (int k = 0; k < 16; ++k)
                    if ((miss & (1u << k)) && (unsigned int)(q[k] >> 32) < tgt)
                        nm |= 1u << k;
                miss = nm;
                if (!miss) break;
                __builtin_amdgcn_s_sleep(1);
            }
            float v[4][4];
            float s1 = 0.f, s2 = 0.f;
#pragma unroll
            for (int g = 0; g < 4; ++g)
#pragma unroll
                for (int e = 0; e < 4; ++e) {
                    float x = __builtin_bit_cast(float, (unsigned int)q[4 * g + e])
                            + bias_r[g][e];
                    v[g][e] = x;
                    s1 += x;
                    s2 += x * x;
                }
            for (int off = 32; off; off >>= 1) {
                s1 += __shfl_down(s1, off);
                s2 += __shfl_down(s2, off);
            }
            if (lane == 0) { red[2 * wv] = s1; red[2 * wv + 1] = s2; }
            __syncthreads();   // collective: ALL producers of this row-block confirmed
            float sum = red[0] + red[2] + red[4] + red[6];
            float ssq = red[1] + red[3] + red[5] + red[7];
            float mean = sum * (1.f / 4096.f);
            float var  = ssq * (1.f / 4096.f) - mean * mean;
            float rstd = rsqrtf(var + 1e-5f);
            float hn[4];
#pragma unroll
            for (int e = 0; e < 4; ++e) {
                float yi = (v[0][e] - mean) * rstd * lnw_r[0][e] + lnb_r[0][e];
                float yf = (v[1][e] - mean) * rstd * lnw_r[1][e] + lnb_r[1][e];
                float yo = (v[2][e] - mean) * rstd * lnw_r[2][e] + lnb_r[2][e];
                float yh = (v[3][e] - mean) * rstd * lnw_r[3][e] + lnb_r[3][e];
                float ig = 1.f / (1.f + __expf(-yi));
                float fg = 1.f / (1.f + __expf(-yf));
                float og = 1.f / (1.f + __expf(-yo));
                float hd = tanhf(yh);
                float cn = fg * cr[e] + ig * hd;
                cr[e] = cn;
                hn[e] = og * tanhf(cn);
            }
            // h handoff (r10 path): one 8B returning xchg, drain, flag, then out
            unsigned long long hp = 0;
#pragma unroll
            for (int e = 0; e < 4; ++e)
                hp |= (unsigned long long)
                      __builtin_bit_cast(unsigned short, __float2bfloat16(hn[e])) << (16 * e);
            xchg8u((unsigned long long*)((unsigned short*)h + b * 1024 + 4 * tid), hp);
            __syncthreads();   // vmcnt(0): h(s) at coherence point
            if (tid == 0)
                __hip_atomic_store(&hflag[b * 16], (unsigned int)(s + 1), AT_RLX, SC_AGT);
            float o4[4];
#pragma unroll
            for (int e = 0; e < 4; ++e) o4[e] = hn[e];
            *(float4*)(out + (size_t)b * 524288 + (size_t)s * 1024 + 4 * tid) =
                *(float4*)o4;
        }
    }
}

// ---------- launcher ----------
extern "C" void kernel_launch(void* const* d_in, const int* in_sizes, int n_in,
                              void* d_out, int out_size, void* d_ws, size_t ws_size,
                              hipStream_t stream) {
    const float* X   = (const float*)d_in[0];   // [64,512,1024]
    const float* W   = (const float*)d_in[1];   // [2048,4096]
    const float* bv  = (const float*)d_in[2];   // [4096]
    const float* lnw = (const float*)d_in[3];   // [4096]
    const float* lnb = (const float*)d_in[4];   // [4096]
    const float* hx  = (const float*)d_in[5];   // [1,1024]
    const float* cx  = (const float*)d_in[6];   // [1,1024]
    float* out = (float*)d_out;                 // [64,512,1024]

    char* base = (char*)d_ws;
    __hip_bfloat16*     Wt    = (__hip_bfloat16*)    (base);             // 16 MB
    __hip_bfloat16*     Xt    = (__hip_bfloat16*)    (base + 16777216);  // 64 MB
    unsigned long long* comb2 = (unsigned long long*)(base + 83886080);  // 2 MB
    __hip_bfloat16*     hbuf  = (__hip_bfloat16*)    (base + 85983232);  // 128 KB
    unsigned int*       hflag = (unsigned int*)      (base + 86114304);  // 4 KB
    // total ~86.12 MB

    conv_w<<<32768, 256, 0, stream>>>(W, Wt);
    conv_x<<<131072, 256, 0, stream>>>(X, Xt);
    init_misc<<<1024, 256, 0, stream>>>(hx, hbuf, comb2, hflag);

    lstm_fused<<<256, 256, 0, stream>>>(Xt, Wt, hbuf, bv, lnw, lnb, cx, comb2, out,
                                        hflag);
}